// Round 1
// baseline (9.963 us; speedup 1.0000x reference)
//
#include <hip/hip_runtime.h>

// TernaryQuantizer collapses analytically:
//   - 729-codebook = tensor product of two 27-trigram sets; squared distance is
//     additively separable -> softmax factorizes -> q_full == q_factored exactly.
//   - gate*q + (1-gate)*q = q  -> gate_logit unused.
//   - Within a 3-dim group, logits separate per scalar dim -> closed form:
//       q(x) = (e^a - e^b) / (1 + e^a + e^b),  a=(2x-1)/T, b=(-2x-1)/T
//   - out = x + BLEND*(q(x) - x),  T=0.3, BLEND=1/1.3
// Pure elementwise map over 786432 f32 elements; memory-bound (~6.3 MB traffic).

#define TQ_TEMP   0.3f
#define TQ_BLEND  (1.0f / 1.3f)

__device__ __forceinline__ float soft_tern(float x) {
    const float invT = 1.0f / TQ_TEMP;
    float a = (2.0f * x - 1.0f) * invT;    // logit for c=+1
    float b = (-2.0f * x - 1.0f) * invT;   // logit for c=-1  (c=0 logit is 0)
    float m = fmaxf(fmaxf(a, b), 0.0f);    // stability shift
    float ea = __expf(a - m);
    float eb = __expf(b - m);
    float e0 = __expf(-m);
    return (ea - eb) / (e0 + ea + eb);     // E[c] under softmax over {-1,0,+1}
}

__device__ __forceinline__ float tq_out(float x) {
    return x + TQ_BLEND * (soft_tern(x) - x);
}

__global__ void __launch_bounds__(256)
tq_kernel(const float* __restrict__ x, float* __restrict__ out, int n) {
    const int n4 = n >> 2;
    const int stride = gridDim.x * blockDim.x;
    for (int i = blockIdx.x * blockDim.x + threadIdx.x; i < n4; i += stride) {
        float4 v = reinterpret_cast<const float4*>(x)[i];
        float4 r;
        r.x = tq_out(v.x);
        r.y = tq_out(v.y);
        r.z = tq_out(v.z);
        r.w = tq_out(v.w);
        reinterpret_cast<float4*>(out)[i] = r;
    }
    // scalar tail (n % 4 elements) — n is 786432 so this is dead, kept for safety
    const int tid = blockIdx.x * blockDim.x + threadIdx.x;
    const int tail = n & 3;
    if (tid < tail) {
        const int idx = (n4 << 2) + tid;
        out[idx] = tq_out(x[idx]);
    }
}

extern "C" void kernel_launch(void* const* d_in, const int* in_sizes, int n_in,
                              void* d_out, int out_size, void* d_ws, size_t ws_size,
                              hipStream_t stream) {
    const float* x = (const float*)d_in[0];   // (16, 8192, 6) f32
    float* out = (float*)d_out;               // same shape f32
    const int n = in_sizes[0];                // 786432

    const int block = 256;
    int n4 = (n + 3) >> 2;
    int grid = (n4 + block - 1) / block;      // 768 for n=786432
    if (grid > 2048) grid = 2048;             // grid-stride beyond this (won't trigger here)
    tq_kernel<<<grid, block, 0, stream>>>(x, out, n);
}